// Round 1
// baseline (861.530 us; speedup 1.0000x reference)
//
#include <hip/hip_runtime.h>
#include <hip/hip_bf16.h>
#include <math.h>

#define B 2048
#define L 100
#define D 256

// ---------------------------------------------------------------------------
// K0: tiny precompute — abs_w[t] = abs_embed[t]·w_abs (t<100),
//     relw[i] = rel_embed[i]·w_rel (i<25), exclusive scan of doc_lens.
// ---------------------------------------------------------------------------
__global__ __launch_bounds__(256) void k0_precompute(
    const float* __restrict__ abs_embed, const float* __restrict__ w_abs,
    const float* __restrict__ rel_embed, const float* __restrict__ w_rel,
    const int* __restrict__ dls,
    float* __restrict__ abs_w, float* __restrict__ relw, int* __restrict__ offs)
{
    int t = threadIdx.x;
    if (t < 100) {
        float s = 0.f;
        for (int j = 0; j < 50; j++) s += abs_embed[t * 50 + j] * w_abs[j];
        abs_w[t] = s;
    }
    if (t < 25) {
        float s = 0.f;
        for (int j = 0; j < 50; j++) s += rel_embed[t * 50 + j] * w_rel[j];
        relw[t] = s;
    }
    // exclusive prefix sum of doc_lens (B = 2048 = 256 threads x 8)
    __shared__ int lds[256];
    int loc[8];
    int sum = 0;
    for (int k = 0; k < 8; k++) { loc[k] = sum; sum += dls[t * 8 + k]; }
    lds[t] = sum;
    __syncthreads();
    for (int off = 1; off < 256; off <<= 1) {
        int v = (t >= off) ? lds[t - off] : 0;
        __syncthreads();
        lds[t] += v;
        __syncthreads();
    }
    int base = (t > 0) ? lds[t - 1] : 0;
    for (int k = 0; k < 8; k++) offs[t * 8 + k] = base + loc[k];
}

// ---------------------------------------------------------------------------
// K1: docs[b,d] = sum_{t<dl} sent[b,t,d] / dl   (one block per doc)
// ---------------------------------------------------------------------------
__global__ __launch_bounds__(256) void k1_docavg(
    const float* __restrict__ sent, const int* __restrict__ dls,
    float* __restrict__ docs)
{
    int b = blockIdx.x, d = threadIdx.x;
    int dl = dls[b];
    const float* p = sent + (size_t)b * L * D + d;
    float s = 0.f;
    int t = 0;
    for (; t + 4 <= dl; t += 4) {
        s += p[(size_t)t * D] + p[(size_t)(t + 1) * D] +
             p[(size_t)(t + 2) * D] + p[(size_t)(t + 3) * D];
    }
    for (; t < dl; t++) s += p[(size_t)t * D];
    docs[b * D + d] = s / (float)dl;
}

// ---------------------------------------------------------------------------
// K2: doc = tanh(docs @ fc_w.T + fc_b); uw = W_sal @ doc + w_content
//     (one block per doc; each thread owns one output dim)
// ---------------------------------------------------------------------------
__global__ __launch_bounds__(256) void k2_docrep(
    const float* __restrict__ docs, const float* __restrict__ fc_w,
    const float* __restrict__ fc_b, const float* __restrict__ W_sal,
    const float* __restrict__ w_content, float* __restrict__ uw)
{
    __shared__ float sd[D];
    __shared__ float sdoc[D];
    int b = blockIdx.x, i = threadIdx.x;
    sd[i] = docs[b * D + i];
    __syncthreads();

    float acc = fc_b[i];
    const float4* wr = (const float4*)(fc_w + (size_t)i * D);
    const float4* dv4 = (const float4*)sd;
#pragma unroll 8
    for (int j = 0; j < D / 4; j++) {
        float4 w = wr[j];
        float4 v = dv4[j];
        acc += w.x * v.x + w.y * v.y + w.z * v.z + w.w * v.w;
    }
    sdoc[i] = tanhf(acc);
    __syncthreads();

    float acc2 = 0.f;
    const float4* wsr = (const float4*)(W_sal + (size_t)i * D);
    const float4* dc4 = (const float4*)sdoc;
#pragma unroll 8
    for (int j = 0; j < D / 4; j++) {
        float4 w = wsr[j];
        float4 v = dc4[j];
        acc2 += w.x * v.x + w.y * v.y + w.z * v.z + w.w * v.w;
    }
    uw[b * D + i] = acc2 + w_content[i];
}

// ---------------------------------------------------------------------------
// K3: G = sent_out @ W_nov   [M=B*L x 256] x [256 x 256], fp32 tiled.
//     64x64 block tile, BK=16, 256 threads, 4x4 microtile per thread.
// ---------------------------------------------------------------------------
__global__ __launch_bounds__(256) void k3_gemm(
    const float* __restrict__ A, const float* __restrict__ W,
    float* __restrict__ G)
{
    __shared__ float As[16][68];  // padded: store bank-spread, rows 16B-aligned (68*4=272=16*17)
    __shared__ float Bs[16][64];

    int tid = threadIdx.x;
    int m0 = blockIdx.x * 64;
    int n0 = blockIdx.y * 64;
    int tx = tid & 15, ty = tid >> 4;

    float acc[4][4];
#pragma unroll
    for (int i = 0; i < 4; i++)
#pragma unroll
        for (int j = 0; j < 4; j++) acc[i][j] = 0.f;

    for (int k0 = 0; k0 < D; k0 += 16) {
#pragma unroll
        for (int i = 0; i < 4; i++) {
            int idx = tid + i * 256;      // 0..1023
            int r = idx >> 4, c = idx & 15;
            As[c][r] = A[(size_t)(m0 + r) * D + k0 + c];
        }
#pragma unroll
        for (int i = 0; i < 4; i++) {
            int idx = tid + i * 256;
            int r = idx >> 6, c = idx & 63;
            Bs[r][c] = W[(size_t)(k0 + r) * D + n0 + c];
        }
        __syncthreads();
#pragma unroll
        for (int k = 0; k < 16; k++) {
            float4 a = *(const float4*)&As[k][ty * 4];
            float4 bv = *(const float4*)&Bs[k][tx * 4];
            acc[0][0] += a.x * bv.x; acc[0][1] += a.x * bv.y; acc[0][2] += a.x * bv.z; acc[0][3] += a.x * bv.w;
            acc[1][0] += a.y * bv.x; acc[1][1] += a.y * bv.y; acc[1][2] += a.y * bv.z; acc[1][3] += a.y * bv.w;
            acc[2][0] += a.z * bv.x; acc[2][1] += a.z * bv.y; acc[2][2] += a.z * bv.z; acc[2][3] += a.z * bv.w;
            acc[3][0] += a.w * bv.x; acc[3][1] += a.w * bv.y; acc[3][2] += a.w * bv.z; acc[3][3] += a.w * bv.w;
        }
        __syncthreads();
    }
#pragma unroll
    for (int i = 0; i < 4; i++) {
        float4 v = make_float4(acc[i][0], acc[i][1], acc[i][2], acc[i][3]);
        *(float4*)&G[(size_t)(m0 + ty * 4 + i) * D + n0 + tx * 4] = v;
    }
}

// ---------------------------------------------------------------------------
// K4: recurrence. One wave per doc; lane l owns dims 4l..4l+3 of s.
//     Per step: pre = h·uw + abs_w[t] + relw[idx] + bias - G_row·tanh(s);
//     p = sigmoid(pre); s += p*h. Only t < dl (later steps can't affect
//     valid outputs). Writes p directly to its packed output slot.
// ---------------------------------------------------------------------------
__global__ __launch_bounds__(256) void k4_recur(
    const float* __restrict__ sent, const float* __restrict__ G,
    const float* __restrict__ uw, const float* __restrict__ abs_w,
    const float* __restrict__ relw, const float* __restrict__ bias,
    const int* __restrict__ dls, const int* __restrict__ offs,
    float* __restrict__ out)
{
    int wave = threadIdx.x >> 6;
    int lane = threadIdx.x & 63;
    int b = blockIdx.x * 4 + wave;

    int dl = dls[b];
    float dlf = (float)dl;
    int base = offs[b];
    float bs = bias[0];

    const float4* h_ptr = (const float4*)(sent + (size_t)b * L * D) + lane;
    const float4* g_ptr = (const float4*)(G + (size_t)b * L * D) + lane;
    float4 uwv = ((const float4*)(uw + (size_t)b * D))[lane];

    float4 s = make_float4(0.f, 0.f, 0.f, 0.f);
    float4 h = h_ptr[0];
    float4 g = g_ptr[0];

    for (int t = 0; t < dl; t++) {
        float4 hn = h, gn = g;
        if (t + 1 < dl) {  // prefetch next step (addresses independent of s)
            hn = h_ptr[(size_t)(t + 1) * (D / 4)];
            gn = g_ptr[(size_t)(t + 1) * (D / 4)];
        }
        float4 ts;
        ts.x = tanhf(s.x); ts.y = tanhf(s.y); ts.z = tanhf(s.z); ts.w = tanhf(s.w);

        float r = h.x * uwv.x + h.y * uwv.y + h.z * uwv.z + h.w * uwv.w
                - (g.x * ts.x + g.y * ts.y + g.z * ts.z + g.w * ts.w);
#pragma unroll
        for (int off = 32; off; off >>= 1) r += __shfl_xor(r, off, 64);

        int idx = (int)rintf((float)(t + 1) * 9.0f / dlf);
        float pre = r + abs_w[t] + relw[idx] + bs;
        float p = 1.0f / (1.0f + __expf(-pre));

        s.x += p * h.x; s.y += p * h.y; s.z += p * h.z; s.w += p * h.w;
        if (lane == 0) out[base + t] = p;
        h = hn; g = gn;
    }
}

// ---------------------------------------------------------------------------
extern "C" void kernel_launch(void* const* d_in, const int* in_sizes, int n_in,
                              void* d_out, int out_size, void* d_ws, size_t ws_size,
                              hipStream_t stream)
{
    const float* sent      = (const float*)d_in[0];
    const float* fc_w      = (const float*)d_in[1];
    const float* fc_b      = (const float*)d_in[2];
    const float* w_content = (const float*)d_in[3];
    const float* W_sal     = (const float*)d_in[4];
    const float* W_nov     = (const float*)d_in[5];
    const float* abs_embed = (const float*)d_in[6];
    const float* rel_embed = (const float*)d_in[7];
    const float* w_abs     = (const float*)d_in[8];
    const float* w_rel     = (const float*)d_in[9];
    const float* bias      = (const float*)d_in[10];
    const int*   dls       = (const int*)d_in[11];
    float* out = (float*)d_out;

    // workspace layout
    char* ws = (char*)d_ws;
    int*   offs  = (int*)ws;                           // 2048 ints  = 8192 B
    float* abs_w = (float*)(ws + 8192);                // 128 floats = 512 B
    float* relw  = (float*)(ws + 8704);                // 32 floats  = 128 B
    float* docs  = (float*)(ws + 8832);                // B*D floats = 2 MiB
    float* uw    = (float*)(ws + 8832 + (size_t)B * D * 4);           // B*D floats
    float* G     = (float*)(ws + 8832 + 2 * (size_t)B * D * 4);       // B*L*D floats

    hipLaunchKernelGGL(k0_precompute, dim3(1), dim3(256), 0, stream,
                       abs_embed, w_abs, rel_embed, w_rel, dls, abs_w, relw, offs);
    hipLaunchKernelGGL(k1_docavg, dim3(B), dim3(256), 0, stream, sent, dls, docs);
    hipLaunchKernelGGL(k2_docrep, dim3(B), dim3(256), 0, stream,
                       docs, fc_w, fc_b, W_sal, w_content, uw);
    hipLaunchKernelGGL(k3_gemm, dim3((B * L) / 64, D / 64), dim3(256), 0, stream,
                       sent, W_nov, G);
    hipLaunchKernelGGL(k4_recur, dim3(B / 4), dim3(256), 0, stream,
                       sent, G, uw, abs_w, relw, bias, dls, offs, out);
}

// Round 3
// 586.197 us; speedup vs baseline: 1.4697x; 1.4697x over previous
//
#include <hip/hip_runtime.h>
#include <hip/hip_bf16.h>
#include <math.h>

#define B 2048
#define L 100
#define D 256

typedef _Float16 half8 __attribute__((ext_vector_type(8)));
typedef __attribute__((ext_vector_type(4))) float f32x4;

// ---------------------------------------------------------------------------
// K0: abs_w[t] = abs_embed[t]·w_abs, relw[i] = rel_embed[i]·w_rel,
//     exclusive scan of doc_lens.
// ---------------------------------------------------------------------------
__global__ __launch_bounds__(256) void k0_precompute(
    const float* __restrict__ abs_embed, const float* __restrict__ w_abs,
    const float* __restrict__ rel_embed, const float* __restrict__ w_rel,
    const int* __restrict__ dls,
    float* __restrict__ abs_w, float* __restrict__ relw, int* __restrict__ offs)
{
    int t = threadIdx.x;
    if (t < 100) {
        float s = 0.f;
        for (int j = 0; j < 50; j++) s += abs_embed[t * 50 + j] * w_abs[j];
        abs_w[t] = s;
    }
    if (t < 25) {
        float s = 0.f;
        for (int j = 0; j < 50; j++) s += rel_embed[t * 50 + j] * w_rel[j];
        relw[t] = s;
    }
    __shared__ int lds[256];
    int loc[8];
    int sum = 0;
    for (int k = 0; k < 8; k++) { loc[k] = sum; sum += dls[t * 8 + k]; }
    lds[t] = sum;
    __syncthreads();
    for (int off = 1; off < 256; off <<= 1) {
        int v = (t >= off) ? lds[t - off] : 0;
        __syncthreads();
        lds[t] += v;
        __syncthreads();
    }
    int base = (t > 0) ? lds[t - 1] : 0;
    for (int k = 0; k < 8; k++) offs[t * 8 + k] = base + loc[k];
}

// ---------------------------------------------------------------------------
// K0b: split-fp16 transpose of W_nov: Wh/Wl are [N][K] fp16,
//      W = Wh + Wl with |err| <= 2^-22 rel.  (2 x 128 KB, L2-resident)
// ---------------------------------------------------------------------------
__global__ __launch_bounds__(256) void k0b_wt(
    const float* __restrict__ W, _Float16* __restrict__ Wh, _Float16* __restrict__ Wl)
{
    int n = blockIdx.x, k = threadIdx.x;
    float w = W[k * D + n];
    _Float16 hi = (_Float16)w;
    _Float16 lo = (_Float16)(w - (float)hi);
    Wh[n * D + k] = hi;
    Wl[n * D + k] = lo;
}

// ---------------------------------------------------------------------------
// K1: docs[b,d] = sum_{t<dl} sent[b,t,d] / dl   (one block per doc)
// ---------------------------------------------------------------------------
__global__ __launch_bounds__(256) void k1_docavg(
    const float* __restrict__ sent, const int* __restrict__ dls,
    float* __restrict__ docs)
{
    int b = blockIdx.x, d = threadIdx.x;
    int dl = dls[b];
    const float* p = sent + (size_t)b * L * D + d;
    float s = 0.f;
    int t = 0;
    for (; t + 4 <= dl; t += 4) {
        s += p[(size_t)t * D] + p[(size_t)(t + 1) * D] +
             p[(size_t)(t + 2) * D] + p[(size_t)(t + 3) * D];
    }
    for (; t < dl; t++) s += p[(size_t)t * D];
    docs[b * D + d] = s / (float)dl;
}

// ---------------------------------------------------------------------------
// K2: doc = tanh(docs @ fc_w.T + fc_b); uw = W_sal @ doc + w_content
//     8 docs per block: weight rows read once per block, reused 8x.
// ---------------------------------------------------------------------------
__global__ __launch_bounds__(256) void k2_docrep(
    const float* __restrict__ docs, const float* __restrict__ fc_w,
    const float* __restrict__ fc_b, const float* __restrict__ W_sal,
    const float* __restrict__ w_content, float* __restrict__ uw)
{
    __shared__ float sd[8][D];
    __shared__ float sdoc[8][D];
    int g = blockIdx.x;
    int i = threadIdx.x;

    for (int dd = 0; dd < 8; dd++) sd[dd][i] = docs[(size_t)(g * 8 + dd) * D + i];
    __syncthreads();

    float acc[8];
    float fb = fc_b[i];
#pragma unroll
    for (int dd = 0; dd < 8; dd++) acc[dd] = fb;
    const float4* wr = (const float4*)(fc_w + (size_t)i * D);
    for (int j = 0; j < D / 4; j++) {
        float4 w = wr[j];
#pragma unroll
        for (int dd = 0; dd < 8; dd++) {
            float4 v = ((const float4*)sd[dd])[j];
            acc[dd] += w.x * v.x + w.y * v.y + w.z * v.z + w.w * v.w;
        }
    }
#pragma unroll
    for (int dd = 0; dd < 8; dd++) sdoc[dd][i] = tanhf(acc[dd]);
    __syncthreads();

    float acc2[8];
#pragma unroll
    for (int dd = 0; dd < 8; dd++) acc2[dd] = 0.f;
    const float4* wsr = (const float4*)(W_sal + (size_t)i * D);
    for (int j = 0; j < D / 4; j++) {
        float4 w = wsr[j];
#pragma unroll
        for (int dd = 0; dd < 8; dd++) {
            float4 v = ((const float4*)sdoc[dd])[j];
            acc2[dd] += w.x * v.x + w.y * v.y + w.z * v.z + w.w * v.w;
        }
    }
    float wc = w_content[i];
#pragma unroll
    for (int dd = 0; dd < 8; dd++)
        uw[(size_t)(g * 8 + dd) * D + i] = acc2[dd] + wc;
}

// ---------------------------------------------------------------------------
// K3: G(fp32) = sent @ W_nov via split-fp16 MFMA (hi*hi + hi*lo + lo*hi).
//     128x128 tile, BK=64, 4 waves x 64x64 quadrants.
//     A: fp32->2xfp16 planes in LDS, XOR-swizzled (conflict-free b128).
//     B: fragments loaded directly from L2-resident Wh/Wl (no staging).
// ---------------------------------------------------------------------------
__global__ __launch_bounds__(256) void k3_mfma(
    const float* __restrict__ A, const _Float16* __restrict__ Wh,
    const _Float16* __restrict__ Wl, float* __restrict__ G)
{
    __shared__ _Float16 Ash[128 * 64];   // 16 KB, hi plane (swizzled)
    __shared__ _Float16 Asl[128 * 64];   // 16 KB, lo plane

    int tid = threadIdx.x;
    int lane = tid & 63;
    int wv = tid >> 6;
    int n0 = blockIdx.x * 128;           // gridDim.x = 2 (n fastest -> L2-hot A)
    int m0 = blockIdx.y * 128;
    int m_off = (wv & 1) * 64;
    int n_off = (wv >> 1) * 64;
    int quad = lane >> 4;
    int l15 = lane & 15;

    f32x4 acc[4][4];
#pragma unroll
    for (int fi = 0; fi < 4; fi++)
#pragma unroll
        for (int fj = 0; fj < 4; fj++) acc[fi][fj] = (f32x4){0.f, 0.f, 0.f, 0.f};

    for (int kk = 0; kk < D; kk += 64) {
        // ---- stage A: 128 rows x 64 K, fp32 -> (hi,lo) fp16 planes ----
#pragma unroll
        for (int i = 0; i < 4; i++) {
            int flat = i * 256 + tid;            // 0..1023 granules
            int r = flat >> 3, g = flat & 7;     // row, 8-half granule
            const float* ap = A + (size_t)(m0 + r) * D + kk + g * 8;
            float4 v0 = *(const float4*)ap;
            float4 v1 = *(const float4*)(ap + 4);
            half8 hh, hl;
            float f[8] = {v0.x, v0.y, v0.z, v0.w, v1.x, v1.y, v1.z, v1.w};
#pragma unroll
            for (int j = 0; j < 8; j++) {
                _Float16 h = (_Float16)f[j];
                hh[j] = h;
                hl[j] = (_Float16)(f[j] - (float)h);
            }
            int pos = r * 64 + ((g ^ (r & 7)) << 3);
            *(half8*)&Ash[pos] = hh;
            *(half8*)&Asl[pos] = hl;
        }
        __syncthreads();

#pragma unroll
        for (int ks = 0; ks < 2; ks++) {
            int gq = ks * 4 + quad;              // K granule 0..7 in BK window
            half8 ah[4], al[4], bh[4], bl[4];
#pragma unroll
            for (int fi = 0; fi < 4; fi++) {
                int r = m_off + fi * 16 + l15;
                int pos = r * 64 + ((gq ^ (r & 7)) << 3);
                ah[fi] = *(const half8*)&Ash[pos];
                al[fi] = *(const half8*)&Asl[pos];
            }
#pragma unroll
            for (int fj = 0; fj < 4; fj++) {
                size_t wo = (size_t)(n0 + n_off + fj * 16 + l15) * D
                          + kk + ks * 32 + quad * 8;
                bh[fj] = *(const half8*)(Wh + wo);
                bl[fj] = *(const half8*)(Wl + wo);
            }
#pragma unroll
            for (int fi = 0; fi < 4; fi++)
#pragma unroll
                for (int fj = 0; fj < 4; fj++) {
                    acc[fi][fj] = __builtin_amdgcn_mfma_f32_16x16x32_f16(
                        ah[fi], bh[fj], acc[fi][fj], 0, 0, 0);
                    acc[fi][fj] = __builtin_amdgcn_mfma_f32_16x16x32_f16(
                        ah[fi], bl[fj], acc[fi][fj], 0, 0, 0);
                    acc[fi][fj] = __builtin_amdgcn_mfma_f32_16x16x32_f16(
                        al[fi], bh[fj], acc[fi][fj], 0, 0, 0);
                }
        }
        __syncthreads();
    }

    // ---- epilogue: direct fp32 stores (C layout: row=quad*4+q, col=l15) ----
#pragma unroll
    for (int fi = 0; fi < 4; fi++)
#pragma unroll
        for (int fj = 0; fj < 4; fj++)
#pragma unroll
            for (int q = 0; q < 4; q++) {
                int row = m0 + m_off + fi * 16 + quad * 4 + q;
                int col = n0 + n_off + fj * 16 + l15;
                G[(size_t)row * D + col] = acc[fi][fj][q];
            }
}

// ---------------------------------------------------------------------------
// K4: recurrence. One wave per doc; lane l owns dims 4l..4l+3 of s.
// ---------------------------------------------------------------------------
__global__ __launch_bounds__(256) void k4_recur(
    const float* __restrict__ sent, const float* __restrict__ G,
    const float* __restrict__ uw, const float* __restrict__ abs_w,
    const float* __restrict__ relw, const float* __restrict__ bias,
    const int* __restrict__ dls, const int* __restrict__ offs,
    float* __restrict__ out)
{
    int wave = threadIdx.x >> 6;
    int lane = threadIdx.x & 63;
    int b = blockIdx.x * 4 + wave;

    int dl = dls[b];
    float dlf = (float)dl;
    int base = offs[b];
    float bs = bias[0];

    const float4* h_ptr = (const float4*)(sent + (size_t)b * L * D) + lane;
    const float4* g_ptr = (const float4*)(G + (size_t)b * L * D) + lane;
    float4 uwv = ((const float4*)(uw + (size_t)b * D))[lane];

    float4 s = make_float4(0.f, 0.f, 0.f, 0.f);
    float4 h = h_ptr[0];
    float4 g = g_ptr[0];

    for (int t = 0; t < dl; t++) {
        float4 hn = h, gn = g;
        if (t + 1 < dl) {  // prefetch (addresses independent of s)
            hn = h_ptr[(size_t)(t + 1) * (D / 4)];
            gn = g_ptr[(size_t)(t + 1) * (D / 4)];
        }
        float4 ts;
        ts.x = tanhf(s.x); ts.y = tanhf(s.y); ts.z = tanhf(s.z); ts.w = tanhf(s.w);

        float r = h.x * uwv.x + h.y * uwv.y + h.z * uwv.z + h.w * uwv.w
                - (g.x * ts.x + g.y * ts.y + g.z * ts.z + g.w * ts.w);
#pragma unroll
        for (int off = 32; off; off >>= 1) r += __shfl_xor(r, off, 64);

        int idx = (int)rintf((float)(t + 1) * 9.0f / dlf);
        float pre = r + abs_w[t] + relw[idx] + bs;
        float p = 1.0f / (1.0f + __expf(-pre));

        s.x += p * h.x; s.y += p * h.y; s.z += p * h.z; s.w += p * h.w;
        if (lane == 0) out[base + t] = p;
        h = hn; g = gn;
    }
}

// ---------------------------------------------------------------------------
extern "C" void kernel_launch(void* const* d_in, const int* in_sizes, int n_in,
                              void* d_out, int out_size, void* d_ws, size_t ws_size,
                              hipStream_t stream)
{
    const float* sent      = (const float*)d_in[0];
    const float* fc_w      = (const float*)d_in[1];
    const float* fc_b      = (const float*)d_in[2];
    const float* w_content = (const float*)d_in[3];
    const float* W_sal     = (const float*)d_in[4];
    const float* W_nov     = (const float*)d_in[5];
    const float* abs_embed = (const float*)d_in[6];
    const float* rel_embed = (const float*)d_in[7];
    const float* w_abs     = (const float*)d_in[8];
    const float* w_rel     = (const float*)d_in[9];
    const float* bias      = (const float*)d_in[10];
    const int*   dls       = (const int*)d_in[11];
    float* out = (float*)d_out;

    // workspace layout (bytes)
    char* ws = (char*)d_ws;
    int*      offs  = (int*)ws;                                   // 8 KiB
    float*    abs_w = (float*)(ws + 8192);                        // 512 B
    float*    relw  = (float*)(ws + 8704);                        // 512 B
    float*    docs  = (float*)(ws + 9216);                        // 2 MiB
    float*    uw    = (float*)(ws + 9216 + (size_t)B * D * 4);    // 2 MiB
    _Float16* Wh    = (_Float16*)(ws + 9216 + 2 * (size_t)B * D * 4);          // 128 KiB
    _Float16* Wl    = (_Float16*)(ws + 9216 + 2 * (size_t)B * D * 4 + 131072); // 128 KiB
    float*    G     = (float*)(ws + 9216 + 2 * (size_t)B * D * 4 + 262144);    // 200 MiB

    hipLaunchKernelGGL(k0_precompute, dim3(1), dim3(256), 0, stream,
                       abs_embed, w_abs, rel_embed, w_rel, dls, abs_w, relw, offs);
    hipLaunchKernelGGL(k0b_wt, dim3(D), dim3(D), 0, stream, W_nov, Wh, Wl);
    hipLaunchKernelGGL(k1_docavg, dim3(B), dim3(256), 0, stream, sent, dls, docs);
    hipLaunchKernelGGL(k2_docrep, dim3(B / 8), dim3(256), 0, stream,
                       docs, fc_w, fc_b, W_sal, w_content, uw);
    hipLaunchKernelGGL(k3_mfma, dim3(2, (B * L) / 128), dim3(256), 0, stream,
                       sent, Wh, Wl, G);
    hipLaunchKernelGGL(k4_recur, dim3(B / 4), dim3(256), 0, stream,
                       sent, G, uw, abs_w, relw, bias, dls, offs, out);
}